// Round 7
// baseline (214.010 us; speedup 1.0000x reference)
//
#include <hip/hip_runtime.h>
#include <hip/hip_bf16.h>

#define E_ 8
#define D_ 1024
#define H_ 4096
#define T_ 512
#define A_ 1024  // total assignments = T_ * top_k
#define BM_ 192  // covers count<=192 in one pass
#define BK_ 64   // fp32 k-chunk

typedef __attribute__((ext_vector_type(8))) short bf16x8;
typedef __attribute__((ext_vector_type(4))) float f32x4;

__device__ __forceinline__ unsigned short f2bf(float f) {
  __hip_bfloat16 h = __float2bfloat16(f);
  return *reinterpret_cast<unsigned short*>(&h);
}

__device__ __forceinline__ bf16x8 pk8(float4 a, float4 b) {
  bf16x8 r;
  r[0] = (short)f2bf(a.x); r[1] = (short)f2bf(a.y);
  r[2] = (short)f2bf(a.z); r[3] = (short)f2bf(a.w);
  r[4] = (short)f2bf(b.x); r[5] = (short)f2bf(b.y);
  r[6] = (short)f2bf(b.z); r[7] = (short)f2bf(b.w);
  return r;
}

// async global->LDS, 16B per lane; dest = wave-uniform base + lane*16
__device__ __forceinline__ void gl16(const void* g, void* l) {
  __builtin_amdgcn_global_load_lds(
      (const __attribute__((address_space(1))) unsigned int*)g,
      (__attribute__((address_space(3))) unsigned int*)l, 16, 0, 0);
}

#define DRAIN_BAR do {                                         \
    asm volatile("s_waitcnt vmcnt(0)" ::: "memory");           \
    __builtin_amdgcn_s_barrier();                              \
    __builtin_amdgcn_sched_barrier(0);                         \
  } while (0)

// ---------------- Router: logits -> softmax -> top2 -> renorm ---------------
__global__ void moe_router(const float* __restrict__ x,
                           const float* __restrict__ gw,
                           int* __restrict__ sel,
                           float* __restrict__ wtop) {
  const int t = blockIdx.x;
  const int lane = threadIdx.x;  // 64
  const float* xr = x + (size_t)t * D_;

  float4 xv[4];
#pragma unroll
  for (int i = 0; i < 4; ++i) xv[i] = *reinterpret_cast<const float4*>(xr + (i * 64 + lane) * 4);

  float lg[E_];
  for (int e = 0; e < E_; ++e) {
    const float* g = gw + (size_t)e * D_;
    float p = 0.f;
#pragma unroll
    for (int i = 0; i < 4; ++i) {
      float4 gv = *reinterpret_cast<const float4*>(g + (i * 64 + lane) * 4);
      p += xv[i].x * gv.x + xv[i].y * gv.y + xv[i].z * gv.z + xv[i].w * gv.w;
    }
#pragma unroll
    for (int off = 32; off; off >>= 1) p += __shfl_xor(p, off);
    lg[e] = p;
  }
  if (lane == 0) {
    float m = lg[0];
    for (int e = 1; e < E_; ++e) m = fmaxf(m, lg[e]);
    float pr[E_];
    float s = 0.f;
    for (int e = 0; e < E_; ++e) { pr[e] = __expf(lg[e] - m); s += pr[e]; }
    const float inv = 1.f / s;
    for (int e = 0; e < E_; ++e) pr[e] *= inv;
    float v0 = -1.f, v1 = -1.f; int i0 = 0, i1 = 0;
    for (int e = 0; e < E_; ++e) {
      float p = pr[e];
      if (p > v0)      { v1 = v0; i1 = i0; v0 = p; i0 = e; }
      else if (p > v1) { v1 = p; i1 = e; }
    }
    const float s2 = 1.f / (v0 + v1);
    sel[2 * t] = i0; sel[2 * t + 1] = i1;
    wtop[2 * t] = v0 * s2; wtop[2 * t + 1] = v1 * s2;
  }
}

// ---------------- Compaction: deterministic, order-preserving ---------------
__global__ void moe_compact(const int* __restrict__ sel,
                            const float* __restrict__ wtop,
                            int* __restrict__ counts,
                            int* __restrict__ offsets,
                            int* __restrict__ tok,
                            int* __restrict__ slotof,
                            float* __restrict__ coef) {
  const int tid = threadIdx.x;  // 512 = 8 waves; wave = expert
  const int e = tid >> 6;
  const int lane = tid & 63;
  __shared__ int cnt[E_], offs[E_];

  int base = 0;
  for (int c = 0; c < T_ / 64; ++c) {
    const int t = c * 64 + lane;
    const bool f = (sel[2 * t] == e) || (sel[2 * t + 1] == e);
    base += __popcll(__ballot(f));
  }
  if (lane == 0) cnt[e] = base;
  __syncthreads();
  if (tid == 0) {
    int o = 0;
    for (int i = 0; i < E_; ++i) { offs[i] = o; o += cnt[i]; }
  }
  __syncthreads();
  if (lane == 0) { counts[e] = cnt[e]; offsets[e] = offs[e]; }

  int pos = offs[e];
  for (int c = 0; c < T_ / 64; ++c) {
    const int t = c * 64 + lane;
    const int s0 = sel[2 * t], s1 = sel[2 * t + 1];
    const bool f = (s0 == e) || (s1 == e);
    unsigned long long b = __ballot(f);
    const int myp = pos + __popcll(b & ((1ull << lane) - 1ull));
    if (f) {
      const int k = (s0 == e) ? 0 : 1;
      tok[myp] = t;
      slotof[2 * t + k] = myp;
      coef[myp] = wtop[2 * t + k];
    }
    pos += __popcll(b);
  }
}

// ---------------- Gather: compacted bf16 activations xc[slot] = x[tok[slot]] -
__global__ void moe_gather(const float* __restrict__ x,
                           const int* __restrict__ tok,
                           unsigned short* __restrict__ xc) {
  const int slot = blockIdx.x;
  const int i = threadIdx.x;  // 256
  const int t = tok[slot];
  float4 v = *reinterpret_cast<const float4*>(x + (size_t)t * D_ + i * 4);
  ushort4 u;
  u.x = f2bf(v.x); u.y = f2bf(v.y); u.z = f2bf(v.z); u.w = f2bf(v.w);
  *reinterpret_cast<ushort4*>(xc + (size_t)slot * D_ + i * 4) = u;
}

// ---------------- FFN kernels --------------------------------------------
// Drain-style 2-phase (best measured structure), DRAM-friendly staging:
// each gl16 = 4 weight rows x 256B CONTIGUOUS; successive iters walk rows
// sequentially. B tile per buf: 64 rows x 64 fp32 (16 KB). Quad-swizzle
// s=(row&6): store src quad li^s (linear LDS dest), read quad q^s; <=4-way
// conflicts. A: compacted bf16 rows, direct global->reg, prefetched 1 iter.

// per-lane staging constants:
//   R = slotrow*4 + (lane>>4)  (slotrow = wid*4+j), li = lane&15
//   src fp32 off = rowbase + kt + ((li ^ (R&6)) << 2)
//   dest fp32 off = slotrow*256 + lane*4   (linear)

#define STAGE1(S, KT)                                                         \
  do {                                                                        \
    _Pragma("unroll")                                                         \
    for (int j = 0; j < 4; ++j) {                                             \
      gl16(b1p[j] + (KT), &B1s[S][(wid * 4 + j) * 256]);                      \
      gl16(b3p[j] + (KT), &B3s[S][(wid * 4 + j) * 256]);                      \
    }                                                                         \
  } while (0)

#define LOADA1(SET, IT)                                                       \
  do {                                                                        \
    _Pragma("unroll")                                                         \
    for (int mf = 0; mf < 3; ++mf) {                                          \
      SET[mf * 2 + 0] = *reinterpret_cast<const bf16x8*>(ap[mf] + (IT) * 64); \
      SET[mf * 2 + 1] = *reinterpret_cast<const bf16x8*>(ap[mf] + (IT) * 64 + 32); \
    }                                                                         \
  } while (0)

// B-frag read: row = nf*16+lr; q = ks*8+kg*2; q' = q ^ (lr&6); idx = row*64+q'*4
#define MFMA1(S, ASET)                                                        \
  do {                                                                        \
    _Pragma("unroll")                                                         \
    for (int ks = 0; ks < 2; ++ks) {                                          \
      _Pragma("unroll")                                                       \
      for (int nf = 0; nf < 4; ++nf) {                                        \
        const int ix = nf * 1024 + (ks ? o1 : o0);                            \
        bf16x8 b1f = pk8(*reinterpret_cast<const float4*>(&B1s[S][ix]),       \
                         *reinterpret_cast<const float4*>(&B1s[S][ix + 4]));  \
        bf16x8 b3f = pk8(*reinterpret_cast<const float4*>(&B3s[S][ix]),       \
                         *reinterpret_cast<const float4*>(&B3s[S][ix + 4]));  \
        _Pragma("unroll")                                                     \
        for (int mf = 0; mf < 3; ++mf)                                        \
          if (mf < mfn) {                                                     \
            acc1[mf][nf] = __builtin_amdgcn_mfma_f32_16x16x32_bf16(ASET[mf * 2 + ks], b1f, acc1[mf][nf], 0, 0, 0); \
            acc3[mf][nf] = __builtin_amdgcn_mfma_f32_16x16x32_bf16(ASET[mf * 2 + ks], b3f, acc3[mf][nf], 0, 0, 0); \
          }                                                                   \
      }                                                                       \
    }                                                                         \
  } while (0)

__launch_bounds__(256, 2)
__global__ void moe_ffn1(const unsigned short* __restrict__ xc,
                         const float* __restrict__ w1,
                         const float* __restrict__ w3,
                         const int* __restrict__ counts,
                         const int* __restrict__ offsets,
                         unsigned short* __restrict__ act) {
  const int bid = blockIdx.x;
  const int e = bid & 7;        // XCD-pinned
  const int hg = bid >> 3;      // 64 h-groups of 64 cols
  const int count = counts[e];
  if (count <= 0) return;
  const int off = offsets[e];
  const int hbase = hg * 64;

  __shared__ float B1s[2][64 * 64];  // 2 x 16 KB
  __shared__ float B3s[2][64 * 64];  // 2 x 16 KB

  const int tid = threadIdx.x;
  const int lane = tid & 63, wid = tid >> 6;
  const int lr = lane & 15, kg = lane >> 4;
  const int wm = wid * 48;

  // staging sources: 4 rows per gl16, 256B contiguous per row
  const float* b1p[4];
  const float* b3p[4];
#pragma unroll
  for (int j = 0; j < 4; ++j) {
    const int R = (wid * 4 + j) * 4 + (lane >> 4);
    const int sc = ((lane & 15) ^ (R & 6)) << 2;
    b1p[j] = w1 + ((size_t)e * H_ + hbase + R) * D_ + sc;
    b3p[j] = w3 + ((size_t)e * H_ + hbase + R) * D_ + sc;
  }
  // swizzled read offsets (fp32 units within a 64-col row)
  const int o0 = lr * 64 + (((kg * 2) ^ (lr & 6)) << 2);
  const int o1 = lr * 64 + (((8 + kg * 2) ^ (lr & 6)) << 2);

  for (int m0 = 0; m0 < count; m0 += BM_) {
    const unsigned short* ap[3];
#pragma unroll
    for (int mf = 0; mf < 3; ++mf) {
      const int row = m0 + wm + mf * 16 + lr;
      const int cr = (row < count) ? row : (count - 1);
      ap[mf] = xc + (size_t)(off + cr) * D_ + kg * 8;
    }
    const int qq = count - m0 - wm;
    const int mfn = (qq <= 0) ? 0 : ((qq + 15) >> 4 < 3 ? (qq + 15) >> 4 : 3);

    f32x4 acc1[3][4] = {};
    f32x4 acc3[3][4] = {};
    bf16x8 aE[6], aO[6];

    STAGE1(0, 0);
    LOADA1(aE, 0);

    for (int it = 0; it < 16; it += 2) {
      DRAIN_BAR;
      if (it + 1 < 16) { STAGE1(1, (it + 1) * BK_); LOADA1(aO, it + 1); }
      MFMA1(0, aE);
      DRAIN_BAR;
      if (it + 2 < 16) { STAGE1(0, (it + 2) * BK_); LOADA1(aE, it + 2); }
      MFMA1(1, aO);
    }

    // Epilogue: silu(h1)*h3 -> bf16 act (compacted rows)
#pragma unroll
    for (int mf = 0; mf < 3; ++mf) {
#pragma unroll
      for (int r = 0; r < 4; ++r) {
        const int mrow = m0 + wm + mf * 16 + kg * 4 + r;
        if (mrow < count) {
          const size_t rb = (size_t)(off + mrow) * H_;
#pragma unroll
          for (int nf = 0; nf < 4; ++nf) {
            const float h1 = acc1[mf][nf][r];
            const float h3 = acc3[mf][nf][r];
            const float a = h1 / (1.f + __expf(-h1)) * h3;
            act[rb + hbase + nf * 16 + lr] = f2bf(a);
          }
        }
      }
    }
    __syncthreads();
  }
}

#define STAGE2(S, KT)                                                         \
  do {                                                                        \
    _Pragma("unroll")                                                         \
    for (int j = 0; j < 4; ++j)                                               \
      gl16(b2p[j] + (KT), &Bs[S][(wid * 4 + j) * 256]);                       \
  } while (0)

#define MFMA2(S, ASET)                                                        \
  do {                                                                        \
    _Pragma("unroll")                                                         \
    for (int ks = 0; ks < 2; ++ks) {                                          \
      _Pragma("unroll")                                                       \
      for (int nf = 0; nf < 4; ++nf) {                                        \
        const int ix = nf * 1024 + (ks ? o1 : o0);                            \
        bf16x8 bf = pk8(*reinterpret_cast<const float4*>(&Bs[S][ix]),         \
                        *reinterpret_cast<const float4*>(&Bs[S][ix + 4]));    \
        _Pragma("unroll")                                                     \
        for (int mf = 0; mf < 3; ++mf)                                        \
          if (mf < mfn)                                                       \
            acc[mf][nf] = __builtin_amdgcn_mfma_f32_16x16x32_bf16(ASET[mf * 2 + ks], bf, acc[mf][nf], 0, 0, 0); \
      }                                                                       \
    }                                                                         \
  } while (0)

__launch_bounds__(256, 2)
__global__ void moe_ffn2(const unsigned short* __restrict__ act,
                         const float* __restrict__ w2,
                         const int* __restrict__ counts,
                         const int* __restrict__ offsets,
                         const float* __restrict__ coef,
                         float* __restrict__ part,
                         int kschunk) {
  const int bid = blockIdx.x;
  const int e = bid & 7;        // XCD-pinned
  const int rest = bid >> 3;
  const int dg = rest & 15;     // 16 d-groups of 64 cols
  const int ks0 = rest >> 4;    // K-split index
  const int count = counts[e];
  if (count <= 0) return;
  const int off = offsets[e];
  const int dbase = dg * 64;
  const int kbase = ks0 * kschunk;
  const int nit = kschunk >> 6;   // BK=64 -> 8/16/32/64 iters (even)

  __shared__ float Bs[2][64 * 64];  // 2 x 16 KB

  const int tid = threadIdx.x;
  const int lane = tid & 63, wid = tid >> 6;
  const int lr = lane & 15, kg = lane >> 4;
  const int wm = wid * 48;

  const float* b2p[4];
#pragma unroll
  for (int j = 0; j < 4; ++j) {
    const int R = (wid * 4 + j) * 4 + (lane >> 4);
    const int sc = ((lane & 15) ^ (R & 6)) << 2;
    b2p[j] = w2 + ((size_t)e * D_ + dbase + R) * H_ + kbase + sc;
  }
  const int o0 = lr * 64 + (((kg * 2) ^ (lr & 6)) << 2);
  const int o1 = lr * 64 + (((8 + kg * 2) ^ (lr & 6)) << 2);

  for (int m0 = 0; m0 < count; m0 += BM_) {
    const unsigned short* ap[3];
#pragma unroll
    for (int mf = 0; mf < 3; ++mf) {
      const int row = m0 + wm + mf * 16 + lr;
      const int cr = (row < count) ? row : (count - 1);
      ap[mf] = act + (size_t)(off + cr) * H_ + kbase + kg * 8;
    }
    const int qq = count - m0 - wm;
    const int mfn = (qq <= 0) ? 0 : ((qq + 15) >> 4 < 3 ? (qq + 15) >> 4 : 3);

    f32x4 acc[3][4] = {};
    bf16x8 aE[6], aO[6];

    STAGE2(0, 0);
    LOADA1(aE, 0);  // same A-load shape as ffn1

    for (int it = 0; it < nit; it += 2) {
      DRAIN_BAR;
      if (it + 1 < nit) { STAGE2(1, (it + 1) * BK_); LOADA1(aO, it + 1); }
      MFMA2(0, aE);
      DRAIN_BAR;
      if (it + 2 < nit) { STAGE2(0, (it + 2) * BK_); LOADA1(aE, it + 2); }
      MFMA2(1, aO);
    }

#pragma unroll
    for (int mf = 0; mf < 3; ++mf) {
#pragma unroll
      for (int r = 0; r < 4; ++r) {
        const int mrow = m0 + wm + mf * 16 + kg * 4 + r;
        if (mrow < count) {
          const float cf = coef[off + mrow];
          float* prow = part + ((size_t)ks0 * A_ + off + mrow) * D_;
#pragma unroll
          for (int nf = 0; nf < 4; ++nf)
            prow[dbase + nf * 16 + lr] = cf * acc[mf][nf][r];
        }
      }
    }
    __syncthreads();
  }
}

// out[t] = sum over (ksn x 2 slots) partials in fixed order -> deterministic
__global__ void moe_combine(const float* __restrict__ part,
                            const int* __restrict__ slotof,
                            float* __restrict__ out,
                            int ksn) {
  const int t = blockIdx.x;
  const int i = threadIdx.x;  // 256 threads, float4 each
  const int g0 = slotof[2 * t], g1 = slotof[2 * t + 1];
  float4 o = make_float4(0.f, 0.f, 0.f, 0.f);
  for (int ks = 0; ks < ksn; ++ks) {
    const float* p = part + (size_t)ks * A_ * D_;
    float4 a = reinterpret_cast<const float4*>(p + (size_t)g0 * D_)[i];
    float4 b = reinterpret_cast<const float4*>(p + (size_t)g1 * D_)[i];
    o.x += a.x + b.x; o.y += a.y + b.y; o.z += a.z + b.z; o.w += a.w + b.w;
  }
  reinterpret_cast<float4*>(out + (size_t)t * D_)[i] = o;
}

extern "C" void kernel_launch(void* const* d_in, const int* in_sizes, int n_in,
                              void* d_out, int out_size, void* d_ws, size_t ws_size,
                              hipStream_t stream) {
  const float* x  = (const float*)d_in[0];
  const float* gw = (const float*)d_in[1];
  const float* w1 = (const float*)d_in[2];
  const float* w3 = (const float*)d_in[3];
  const float* w2 = (const float*)d_in[4];
  float* out = (float*)d_out;

  char* ws = (char*)d_ws;
  const size_t SM  = 32768;
  const size_t XC  = (size_t)A_ * D_ * 2;   // 2 MB bf16 compacted activations
  const size_t ACT = (size_t)A_ * H_ * 2;   // 8 MB bf16
  const size_t P1  = (size_t)A_ * D_ * 4;   // 4 MB fp32 per K-split

  char* sm = ws;
  unsigned short* xc  = (unsigned short*)(ws + SM);
  unsigned short* act = (unsigned short*)(ws + SM + XC);
  float* part         = (float*)(ws + SM + XC + ACT);
  const size_t base = SM + XC + ACT;
  const int ksn = (ws_size >= base + 8 * P1) ? 8 :
                  (ws_size >= base + 4 * P1) ? 4 :
                  (ws_size >= base + 2 * P1) ? 2 : 1;

  int*   sel     = (int*)  (sm);
  float* wtop    = (float*)(sm + 4096);
  int*   counts  = (int*)  (sm + 8192);
  int*   offsets = (int*)  (sm + 8192 + 64);
  int*   tokl    = (int*)  (sm + 12288);
  int*   slotof  = (int*)  (sm + 16384);
  float* coef    = (float*)(sm + 20480);

  moe_router <<<T_, 64, 0, stream>>>(x, gw, sel, wtop);
  moe_compact<<<1, 512, 0, stream>>>(sel, wtop, counts, offsets, tokl, slotof, coef);
  moe_gather <<<A_, 256, 0, stream>>>(x, tokl, xc);
  moe_ffn1   <<<E_ * 64, 256, 0, stream>>>(xc, w1, w3, counts, offsets, act);
  moe_ffn2   <<<E_ * 16 * ksn, 256, 0, stream>>>(act, w2, counts, offsets, coef, part, H_ / ksn);
  moe_combine<<<T_, 256, 0, stream>>>(part, slotof, out, ksn);
}

// Round 9
// 181.913 us; speedup vs baseline: 1.1764x; 1.1764x over previous
//
#include <hip/hip_runtime.h>
#include <hip/hip_bf16.h>

#define E_ 8
#define D_ 1024
#define H_ 4096
#define T_ 512
#define A_ 1024  // total assignments = T_ * top_k

typedef __attribute__((ext_vector_type(8))) short bf16x8;
typedef __attribute__((ext_vector_type(4))) float f32x4;
typedef __attribute__((ext_vector_type(8))) unsigned short u16x8;

__device__ __forceinline__ unsigned short f2bf(float f) {
  __hip_bfloat16 h = __float2bfloat16(f);
  return *reinterpret_cast<unsigned short*>(&h);
}

__device__ __forceinline__ u16x8 pack8(float4 a, float4 b) {
  u16x8 r;
  r[0] = f2bf(a.x); r[1] = f2bf(a.y); r[2] = f2bf(a.z); r[3] = f2bf(a.w);
  r[4] = f2bf(b.x); r[5] = f2bf(b.y); r[6] = f2bf(b.z); r[7] = f2bf(b.w);
  return r;
}

// ---------------- Router: logits -> softmax -> top2 -> renorm; x -> bf16 ----
__global__ void moe_router(const float* __restrict__ x,
                           const float* __restrict__ gw,
                           unsigned short* __restrict__ xb,
                           int* __restrict__ sel,
                           float* __restrict__ wtop) {
  const int t = blockIdx.x;
  const int lane = threadIdx.x;  // 64
  const float* xr = x + (size_t)t * D_;

  float4 xv[4];
#pragma unroll
  for (int i = 0; i < 4; ++i) xv[i] = *reinterpret_cast<const float4*>(xr + (i * 64 + lane) * 4);
#pragma unroll
  for (int i = 0; i < 4; ++i) {
    ushort4 u;
    u.x = f2bf(xv[i].x); u.y = f2bf(xv[i].y); u.z = f2bf(xv[i].z); u.w = f2bf(xv[i].w);
    *reinterpret_cast<ushort4*>(xb + (size_t)t * D_ + (i * 64 + lane) * 4) = u;
  }

  float lg[E_];
  for (int e = 0; e < E_; ++e) {
    const float* g = gw + (size_t)e * D_;
    float p = 0.f;
#pragma unroll
    for (int i = 0; i < 4; ++i) {
      float4 gv = *reinterpret_cast<const float4*>(g + (i * 64 + lane) * 4);
      p += xv[i].x * gv.x + xv[i].y * gv.y + xv[i].z * gv.z + xv[i].w * gv.w;
    }
#pragma unroll
    for (int off = 32; off; off >>= 1) p += __shfl_xor(p, off);
    lg[e] = p;
  }
  if (lane == 0) {
    float m = lg[0];
    for (int e = 1; e < E_; ++e) m = fmaxf(m, lg[e]);
    float pr[E_];
    float s = 0.f;
    for (int e = 0; e < E_; ++e) { pr[e] = __expf(lg[e] - m); s += pr[e]; }
    const float inv = 1.f / s;
    for (int e = 0; e < E_; ++e) pr[e] *= inv;
    float v0 = -1.f, v1 = -1.f; int i0 = 0, i1 = 0;
    for (int e = 0; e < E_; ++e) {
      float p = pr[e];
      if (p > v0)      { v1 = v0; i1 = i0; v0 = p; i0 = e; }
      else if (p > v1) { v1 = p; i1 = e; }
    }
    const float s2 = 1.f / (v0 + v1);
    sel[2 * t] = i0; sel[2 * t + 1] = i1;
    wtop[2 * t] = v0 * s2; wtop[2 * t + 1] = v1 * s2;
  }
}

// ---------------- Compaction: deterministic, order-preserving ---------------
__global__ void moe_compact(const int* __restrict__ sel,
                            const float* __restrict__ wtop,
                            int* __restrict__ counts,
                            int* __restrict__ offsets,
                            int* __restrict__ tok,
                            int* __restrict__ slotof,
                            float* __restrict__ coef) {
  const int tid = threadIdx.x;  // 512 = 8 waves; wave = expert
  const int e = tid >> 6;
  const int lane = tid & 63;
  __shared__ int cnt[E_], offs[E_];

  int base = 0;
  for (int c = 0; c < T_ / 64; ++c) {
    const int t = c * 64 + lane;
    const bool f = (sel[2 * t] == e) || (sel[2 * t + 1] == e);
    base += __popcll(__ballot(f));
  }
  if (lane == 0) cnt[e] = base;
  __syncthreads();
  if (tid == 0) {
    int o = 0;
    for (int i = 0; i < E_; ++i) { offs[i] = o; o += cnt[i]; }
  }
  __syncthreads();
  if (lane == 0) { counts[e] = cnt[e]; offsets[e] = offs[e]; }

  int pos = offs[e];
  for (int c = 0; c < T_ / 64; ++c) {
    const int t = c * 64 + lane;
    const int s0 = sel[2 * t], s1 = sel[2 * t + 1];
    const bool f = (s0 == e) || (s1 == e);
    unsigned long long b = __ballot(f);
    const int myp = pos + __popcll(b & ((1ull << lane) - 1ull));
    if (f) {
      const int k = (s0 == e) ? 0 : 1;
      tok[myp] = t;
      slotof[2 * t + k] = myp;
      coef[myp] = wtop[2 * t + k];
    }
    pos += __popcll(b);
  }
}

// ---------------- FFN kernels: r3 barrier-staged skeleton + T14 prefetch ----
// BM=192 (one tile covers count<=192), BN=64, BK=64, padded LDS [.][72].
// T14: iter t+1's global loads are issued into a SECOND register set during
// iter t's compute phase, hiding load latency under compute+syncs.
#define BM_ 192
#define LDA_ 72

#define LOADR1(AV, B1V, B3V, KT) do {                                         \
    _Pragma("unroll")                                                         \
    for (int i = 0; i < 6; ++i) AV[i] = *reinterpret_cast<const u16x8*>(arow[i] + (KT)); \
    _Pragma("unroll")                                                         \
    for (int i = 0; i < 4; ++i) {                                             \
      B1V[i] = *reinterpret_cast<const float4*>(W1p + (KT) + i * 4);          \
      B3V[i] = *reinterpret_cast<const float4*>(W3p + (KT) + i * 4);          \
    }                                                                         \
  } while (0)

#define WRITE1(AV, B1V, B3V) do {                                             \
    _Pragma("unroll")                                                         \
    for (int i = 0; i < 6; ++i)                                               \
      *reinterpret_cast<u16x8*>(&As[i * 32 + (tid >> 3)][(tid & 7) * 8]) = AV[i]; \
    _Pragma("unroll")                                                         \
    for (int i = 0; i < 2; ++i) {                                             \
      *reinterpret_cast<u16x8*>(&B1s[brow][bcol + i * 8]) = pack8(B1V[2 * i], B1V[2 * i + 1]); \
      *reinterpret_cast<u16x8*>(&B3s[brow][bcol + i * 8]) = pack8(B3V[2 * i], B3V[2 * i + 1]); \
    }                                                                         \
  } while (0)

#define COMPUTE1() do {                                                       \
    _Pragma("unroll")                                                         \
    for (int ks = 0; ks < 2; ++ks) {                                          \
      const int kc = ks * 32 + kg * 8;                                        \
      bf16x8 af[3];                                                           \
      _Pragma("unroll")                                                       \
      for (int mf = 0; mf < 3; ++mf)                                          \
        af[mf] = *reinterpret_cast<const bf16x8*>(&As[wm + mf * 16 + lr][kc]); \
      _Pragma("unroll")                                                       \
      for (int nf = 0; nf < 4; ++nf) {                                        \
        bf16x8 b1f = *reinterpret_cast<const bf16x8*>(&B1s[nf * 16 + lr][kc]); \
        bf16x8 b3f = *reinterpret_cast<const bf16x8*>(&B3s[nf * 16 + lr][kc]); \
        _Pragma("unroll")                                                     \
        for (int mf = 0; mf < 3; ++mf)                                        \
          if (mf < mfn) {                                                     \
            acc1[mf][nf] = __builtin_amdgcn_mfma_f32_16x16x32_bf16(af[mf], b1f, acc1[mf][nf], 0, 0, 0); \
            acc3[mf][nf] = __builtin_amdgcn_mfma_f32_16x16x32_bf16(af[mf], b3f, acc3[mf][nf], 0, 0, 0); \
          }                                                                   \
      }                                                                       \
    }                                                                         \
  } while (0)

__launch_bounds__(256, 2)
__global__ void moe_ffn1(const unsigned short* __restrict__ xb,
                         const float* __restrict__ w1,
                         const float* __restrict__ w3,
                         const int* __restrict__ counts,
                         const int* __restrict__ offsets,
                         const int* __restrict__ tok,
                         unsigned short* __restrict__ act) {
  const int bid = blockIdx.x;
  const int hg = bid & 63;
  const int e = bid >> 6;
  const int count = counts[e];
  if (count <= 0) return;
  const int off = offsets[e];

  __shared__ unsigned short As[BM_][LDA_];
  __shared__ unsigned short B1s[64][LDA_];
  __shared__ unsigned short B3s[64][LDA_];

  const int tid = threadIdx.x;
  const int lane = tid & 63, wid = tid >> 6;
  const int lr = lane & 15, kg = lane >> 4;
  const int wm = wid * 48;
  const int hbase = hg * 64;

  const int brow = tid >> 2, bcol = (tid & 3) * 16;
  const float* W1p = w1 + ((size_t)e * H_ + hbase + brow) * D_ + bcol;
  const float* W3p = w3 + ((size_t)e * H_ + hbase + brow) * D_ + bcol;

  for (int m0 = 0; m0 < count; m0 += BM_) {
    const int mc = count - m0;
    const unsigned short* arow[6];
#pragma unroll
    for (int i = 0; i < 6; ++i) {
      const int r = i * 32 + (tid >> 3);
      const int cr = (m0 + r < count) ? (m0 + r) : (count - 1);
      arow[i] = xb + (size_t)tok[off + cr] * D_ + (tid & 7) * 8;
    }
    const int q = mc - wm;
    const int mfn = (q <= 0) ? 0 : ((q + 15) >> 4 < 3 ? (q + 15) >> 4 : 3);

    f32x4 acc1[3][4] = {};
    f32x4 acc3[3][4] = {};

    u16x8 avE[6], avO[6];
    float4 b1E[4], b3E[4], b1O[4], b3O[4];

    LOADR1(avE, b1E, b3E, 0);

    for (int kt = 0; kt < D_; kt += 128) {
      __syncthreads();
      WRITE1(avE, b1E, b3E);
      __syncthreads();
      LOADR1(avO, b1O, b3O, kt + 64);
      COMPUTE1();

      __syncthreads();
      WRITE1(avO, b1O, b3O);
      __syncthreads();
      if (kt + 128 < D_) LOADR1(avE, b1E, b3E, kt + 128);
      COMPUTE1();
    }

    // Epilogue: silu(h1)*h3 -> bf16 act
#pragma unroll
    for (int mf = 0; mf < 3; ++mf) {
#pragma unroll
      for (int r = 0; r < 4; ++r) {
        const int mrow = m0 + wm + mf * 16 + kg * 4 + r;
        if (mrow < count) {
          const size_t rb = (size_t)(off + mrow) * H_;
#pragma unroll
          for (int nf = 0; nf < 4; ++nf) {
            const float h1 = acc1[mf][nf][r];
            const float h3 = acc3[mf][nf][r];
            const float a = h1 / (1.f + __expf(-h1)) * h3;
            act[rb + hbase + nf * 16 + lr] = f2bf(a);
          }
        }
      }
    }
  }
}

#define LOADR2(AV, BV, KT) do {                                               \
    _Pragma("unroll")                                                         \
    for (int i = 0; i < 6; ++i) AV[i] = *reinterpret_cast<const u16x8*>(arow[i] + (KT)); \
    _Pragma("unroll")                                                         \
    for (int i = 0; i < 4; ++i) BV[i] = *reinterpret_cast<const float4*>(W2p + (KT) + i * 4); \
  } while (0)

#define WRITE2(AV, BV) do {                                                   \
    _Pragma("unroll")                                                         \
    for (int i = 0; i < 6; ++i)                                               \
      *reinterpret_cast<u16x8*>(&As[i * 32 + (tid >> 3)][(tid & 7) * 8]) = AV[i]; \
    _Pragma("unroll")                                                         \
    for (int i = 0; i < 2; ++i)                                               \
      *reinterpret_cast<u16x8*>(&Bs[brow][bcol + i * 8]) = pack8(BV[2 * i], BV[2 * i + 1]); \
  } while (0)

#define COMPUTE2() do {                                                       \
    _Pragma("unroll")                                                         \
    for (int ks2 = 0; ks2 < 2; ++ks2) {                                       \
      const int kc = ks2 * 32 + kg * 8;                                       \
      bf16x8 af[3];                                                           \
      _Pragma("unroll")                                                       \
      for (int mf = 0; mf < 3; ++mf)                                          \
        af[mf] = *reinterpret_cast<const bf16x8*>(&As[wm + mf * 16 + lr][kc]); \
      _Pragma("unroll")                                                       \
      for (int nf = 0; nf < 4; ++nf) {                                        \
        bf16x8 bf = *reinterpret_cast<const bf16x8*>(&Bs[nf * 16 + lr][kc]);  \
        _Pragma("unroll")                                                     \
        for (int mf = 0; mf < 3; ++mf)                                        \
          if (mf < mfn)                                                       \
            acc[mf][nf] = __builtin_amdgcn_mfma_f32_16x16x32_bf16(af[mf], bf, acc[mf][nf], 0, 0, 0); \
      }                                                                       \
    }                                                                         \
  } while (0)

__launch_bounds__(256, 2)
__global__ void moe_ffn2(const unsigned short* __restrict__ act,
                         const float* __restrict__ w2,
                         const int* __restrict__ counts,
                         const int* __restrict__ offsets,
                         const float* __restrict__ coef,
                         float* __restrict__ part,
                         int kschunk) {
  const int bid = blockIdx.x;
  const int ks = bid >> 7;
  const int e = (bid >> 4) & 7;
  const int dg = bid & 15;
  const int count = counts[e];
  if (count <= 0) return;
  const int off = offsets[e];
  const int kbase = ks * kschunk;

  __shared__ unsigned short As[BM_][LDA_];
  __shared__ unsigned short Bs[64][LDA_];

  const int tid = threadIdx.x;
  const int lane = tid & 63, wid = tid >> 6;
  const int lr = lane & 15, kg = lane >> 4;
  const int wm = wid * 48;
  const int dbase = dg * 64;

  const int brow = tid >> 2, bcol = (tid & 3) * 16;
  const float* W2p = w2 + ((size_t)e * D_ + dbase + brow) * H_ + kbase + bcol;

  for (int m0 = 0; m0 < count; m0 += BM_) {
    const int mc = count - m0;
    const unsigned short* arow[6];
#pragma unroll
    for (int i = 0; i < 6; ++i) {
      const int r = i * 32 + (tid >> 3);
      const int cr = (m0 + r < count) ? (m0 + r) : (count - 1);
      arow[i] = act + (size_t)(off + cr) * H_ + kbase + (tid & 7) * 8;
    }
    const int q = mc - wm;
    const int mfn = (q <= 0) ? 0 : ((q + 15) >> 4 < 3 ? (q + 15) >> 4 : 3);

    f32x4 acc[3][4] = {};

    u16x8 avE[6], avO[6];
    float4 bE[4], bO[4];

    LOADR2(avE, bE, 0);

    for (int kt = 0; kt < kschunk; kt += 128) {
      __syncthreads();
      WRITE2(avE, bE);
      __syncthreads();
      LOADR2(avO, bO, kt + 64);
      COMPUTE2();

      __syncthreads();
      WRITE2(avO, bO);
      __syncthreads();
      if (kt + 128 < kschunk) LOADR2(avE, bE, kt + 128);
      COMPUTE2();
    }

#pragma unroll
    for (int mf = 0; mf < 3; ++mf) {
#pragma unroll
      for (int r = 0; r < 4; ++r) {
        const int mrow = m0 + wm + mf * 16 + kg * 4 + r;
        if (mrow < count) {
          const float cf = coef[off + mrow];
          float* prow = part + ((size_t)ks * A_ + off + mrow) * D_;
#pragma unroll
          for (int nf = 0; nf < 4; ++nf)
            prow[dbase + nf * 16 + lr] = cf * acc[mf][nf][r];
        }
      }
    }
  }
}

// out[t] = sum over (ksn x 2 slots) partials in fixed order -> deterministic
__global__ void moe_combine(const float* __restrict__ part,
                            const int* __restrict__ slotof,
                            float* __restrict__ out,
                            int ksn) {
  const int t = blockIdx.x;
  const int i = threadIdx.x;  // 256 threads, float4 each
  const int g0 = slotof[2 * t], g1 = slotof[2 * t + 1];
  float4 o = make_float4(0.f, 0.f, 0.f, 0.f);
  for (int ks = 0; ks < ksn; ++ks) {
    const float* p = part + (size_t)ks * A_ * D_;
    float4 a = reinterpret_cast<const float4*>(p + (size_t)g0 * D_)[i];
    float4 b = reinterpret_cast<const float4*>(p + (size_t)g1 * D_)[i];
    o.x += a.x + b.x; o.y += a.y + b.y; o.z += a.z + b.z; o.w += a.w + b.w;
  }
  reinterpret_cast<float4*>(out + (size_t)t * D_)[i] = o;
}

extern "C" void kernel_launch(void* const* d_in, const int* in_sizes, int n_in,
                              void* d_out, int out_size, void* d_ws, size_t ws_size,
                              hipStream_t stream) {
  const float* x  = (const float*)d_in[0];
  const float* gw = (const float*)d_in[1];
  const float* w1 = (const float*)d_in[2];
  const float* w3 = (const float*)d_in[3];
  const float* w2 = (const float*)d_in[4];
  float* out = (float*)d_out;

  char* ws = (char*)d_ws;
  const size_t SM   = 32768;
  const size_t ACT  = (size_t)A_ * H_ * 2;   // 8 MB bf16
  const size_t XB   = (size_t)T_ * D_ * 2;   // 1 MB bf16
  const size_t P1   = (size_t)A_ * D_ * 4;   // 4 MB fp32 per K-split

  char* sm = ws;
  unsigned short* act = (unsigned short*)(ws + SM);
  unsigned short* xb  = (unsigned short*)(ws + SM + ACT);
  float* part         = (float*)(ws + SM + ACT + XB);
  const size_t base = SM + ACT + XB;
  const int ksn = (ws_size >= base + 4 * P1) ? 4 : (ws_size >= base + 2 * P1) ? 2 : 1;

  int*   sel     = (int*)  (sm);
  float* wtop    = (float*)(sm + 4096);
  int*   counts  = (int*)  (sm + 8192);
  int*   offsets = (int*)  (sm + 8192 + 64);
  int*   tokl    = (int*)  (sm + 12288);
  int*   slotof  = (int*)  (sm + 16384);
  float* coef    = (float*)(sm + 20480);

  moe_router <<<T_, 64, 0, stream>>>(x, gw, xb, sel, wtop);
  moe_compact<<<1, 512, 0, stream>>>(sel, wtop, counts, offsets, tokl, slotof, coef);
  moe_ffn1   <<<E_ * 64, 256, 0, stream>>>(xb, w1, w3, counts, offsets, tokl, act);
  moe_ffn2   <<<128 * ksn, 256, 0, stream>>>(act, w2, counts, offsets, coef, part, H_ / ksn);
  moe_combine<<<T_, 256, 0, stream>>>(part, slotof, out, ksn);
}

// Round 10
// 177.514 us; speedup vs baseline: 1.2056x; 1.0248x over previous
//
#include <hip/hip_runtime.h>
#include <hip/hip_bf16.h>

#define E_ 8
#define D_ 1024
#define H_ 4096
#define T_ 512
#define A_ 1024  // total assignments = T_ * top_k

typedef __attribute__((ext_vector_type(8))) short bf16x8;
typedef __attribute__((ext_vector_type(4))) float f32x4;
typedef __attribute__((ext_vector_type(8))) unsigned short u16x8;

__device__ __forceinline__ unsigned short f2bf(float f) {
  __hip_bfloat16 h = __float2bfloat16(f);
  return *reinterpret_cast<unsigned short*>(&h);
}

__device__ __forceinline__ ushort4 pack4(float4 a) {
  ushort4 u;
  u.x = f2bf(a.x); u.y = f2bf(a.y); u.z = f2bf(a.z); u.w = f2bf(a.w);
  return u;
}

// ---------------- Router: logits -> softmax -> top2 -> renorm; x -> bf16 ----
__global__ void moe_router(const float* __restrict__ x,
                           const float* __restrict__ gw,
                           unsigned short* __restrict__ xb,
                           int* __restrict__ sel,
                           float* __restrict__ wtop) {
  const int t = blockIdx.x;
  const int lane = threadIdx.x;  // 64
  const float* xr = x + (size_t)t * D_;

  float4 xv[4];
#pragma unroll
  for (int i = 0; i < 4; ++i) xv[i] = *reinterpret_cast<const float4*>(xr + (i * 64 + lane) * 4);
#pragma unroll
  for (int i = 0; i < 4; ++i) {
    ushort4 u;
    u.x = f2bf(xv[i].x); u.y = f2bf(xv[i].y); u.z = f2bf(xv[i].z); u.w = f2bf(xv[i].w);
    *reinterpret_cast<ushort4*>(xb + (size_t)t * D_ + (i * 64 + lane) * 4) = u;
  }

  float lg[E_];
  for (int e = 0; e < E_; ++e) {
    const float* g = gw + (size_t)e * D_;
    float p = 0.f;
#pragma unroll
    for (int i = 0; i < 4; ++i) {
      float4 gv = *reinterpret_cast<const float4*>(g + (i * 64 + lane) * 4);
      p += xv[i].x * gv.x + xv[i].y * gv.y + xv[i].z * gv.z + xv[i].w * gv.w;
    }
#pragma unroll
    for (int off = 32; off; off >>= 1) p += __shfl_xor(p, off);
    lg[e] = p;
  }
  if (lane == 0) {
    float m = lg[0];
    for (int e = 1; e < E_; ++e) m = fmaxf(m, lg[e]);
    float pr[E_];
    float s = 0.f;
    for (int e = 0; e < E_; ++e) { pr[e] = __expf(lg[e] - m); s += pr[e]; }
    const float inv = 1.f / s;
    for (int e = 0; e < E_; ++e) pr[e] *= inv;
    float v0 = -1.f, v1 = -1.f; int i0 = 0, i1 = 0;
    for (int e = 0; e < E_; ++e) {
      float p = pr[e];
      if (p > v0)      { v1 = v0; i1 = i0; v0 = p; i0 = e; }
      else if (p > v1) { v1 = p; i1 = e; }
    }
    const float s2 = 1.f / (v0 + v1);
    sel[2 * t] = i0; sel[2 * t + 1] = i1;
    wtop[2 * t] = v0 * s2; wtop[2 * t + 1] = v1 * s2;
  }
}

// ---------------- Compaction: deterministic, order-preserving ---------------
__global__ void moe_compact(const int* __restrict__ sel,
                            const float* __restrict__ wtop,
                            int* __restrict__ counts,
                            int* __restrict__ offsets,
                            int* __restrict__ tok,
                            int* __restrict__ slotof,
                            float* __restrict__ coef) {
  const int tid = threadIdx.x;  // 512 = 8 waves; wave = expert
  const int e = tid >> 6;
  const int lane = tid & 63;
  __shared__ int cnt[E_], offs[E_];

  int base = 0;
  for (int c = 0; c < T_ / 64; ++c) {
    const int t = c * 64 + lane;
    const bool f = (sel[2 * t] == e) || (sel[2 * t + 1] == e);
    base += __popcll(__ballot(f));
  }
  if (lane == 0) cnt[e] = base;
  __syncthreads();
  if (tid == 0) {
    int o = 0;
    for (int i = 0; i < E_; ++i) { offs[i] = o; o += cnt[i]; }
  }
  __syncthreads();
  if (lane == 0) { counts[e] = cnt[e]; offsets[e] = offs[e]; }

  int pos = offs[e];
  for (int c = 0; c < T_ / 64; ++c) {
    const int t = c * 64 + lane;
    const int s0 = sel[2 * t], s1 = sel[2 * t + 1];
    const bool f = (s0 == e) || (s1 == e);
    unsigned long long b = __ballot(f);
    const int myp = pos + __popcll(b & ((1ull << lane) - 1ull));
    if (f) {
      const int k = (s0 == e) ? 0 : 1;
      tok[myp] = t;
      slotof[2 * t + k] = myp;
      coef[myp] = wtop[2 * t + k];
    }
    pos += __popcll(b);
  }
}

// ---------------- FFN kernels: r3 skeleton, line-coalesced B loads ----------
// BM=192, BN=64, BK=64, padded LDS [.][72]. ONLY change vs r3: B-load mapping
// is row = j*16 + (tid>>4), col = (tid&15)*4 fp32 -> each wave instruction
// covers 4 rows x 256B fully contiguous (2 full 128B lines, requested once,
// 100% coverage, no cross-instruction line assembly).
#define BM_ 192
#define LDA_ 72

#define LOADR1(AV, B1V, B3V, KT) do {                                         \
    _Pragma("unroll")                                                         \
    for (int i = 0; i < 6; ++i) AV[i] = *reinterpret_cast<const u16x8*>(arow[i] + (KT)); \
    _Pragma("unroll")                                                         \
    for (int j = 0; j < 4; ++j) {                                             \
      B1V[j] = *reinterpret_cast<const float4*>(W1p + (KT) + j * 16 * D_);    \
      B3V[j] = *reinterpret_cast<const float4*>(W3p + (KT) + j * 16 * D_);    \
    }                                                                         \
  } while (0)

#define WRITE1(AV, B1V, B3V) do {                                             \
    _Pragma("unroll")                                                         \
    for (int i = 0; i < 6; ++i)                                               \
      *reinterpret_cast<u16x8*>(&As[i * 32 + (tid >> 3)][(tid & 7) * 8]) = AV[i]; \
    _Pragma("unroll")                                                         \
    for (int j = 0; j < 4; ++j) {                                             \
      *reinterpret_cast<ushort4*>(&B1s[j * 16 + (tid >> 4)][(tid & 15) * 4]) = pack4(B1V[j]); \
      *reinterpret_cast<ushort4*>(&B3s[j * 16 + (tid >> 4)][(tid & 15) * 4]) = pack4(B3V[j]); \
    }                                                                         \
  } while (0)

#define COMPUTE1() do {                                                       \
    _Pragma("unroll")                                                         \
    for (int ks = 0; ks < 2; ++ks) {                                          \
      const int kc = ks * 32 + kg * 8;                                        \
      bf16x8 af[3];                                                           \
      _Pragma("unroll")                                                       \
      for (int mf = 0; mf < 3; ++mf)                                          \
        af[mf] = *reinterpret_cast<const bf16x8*>(&As[wm + mf * 16 + lr][kc]); \
      _Pragma("unroll")                                                       \
      for (int nf = 0; nf < 4; ++nf) {                                        \
        bf16x8 b1f = *reinterpret_cast<const bf16x8*>(&B1s[nf * 16 + lr][kc]); \
        bf16x8 b3f = *reinterpret_cast<const bf16x8*>(&B3s[nf * 16 + lr][kc]); \
        _Pragma("unroll")                                                     \
        for (int mf = 0; mf < 3; ++mf)                                        \
          if (mf < mfn) {                                                     \
            acc1[mf][nf] = __builtin_amdgcn_mfma_f32_16x16x32_bf16(af[mf], b1f, acc1[mf][nf], 0, 0, 0); \
            acc3[mf][nf] = __builtin_amdgcn_mfma_f32_16x16x32_bf16(af[mf], b3f, acc3[mf][nf], 0, 0, 0); \
          }                                                                   \
      }                                                                       \
    }                                                                         \
  } while (0)

__launch_bounds__(256, 2)
__global__ void moe_ffn1(const unsigned short* __restrict__ xb,
                         const float* __restrict__ w1,
                         const float* __restrict__ w3,
                         const int* __restrict__ counts,
                         const int* __restrict__ offsets,
                         const int* __restrict__ tok,
                         unsigned short* __restrict__ act) {
  const int bid = blockIdx.x;
  const int hg = bid & 63;
  const int e = bid >> 6;
  const int count = counts[e];
  if (count <= 0) return;
  const int off = offsets[e];

  __shared__ unsigned short As[BM_][LDA_];
  __shared__ unsigned short B1s[64][LDA_];
  __shared__ unsigned short B3s[64][LDA_];

  const int tid = threadIdx.x;
  const int lane = tid & 63, wid = tid >> 6;
  const int lr = lane & 15, kg = lane >> 4;
  const int wm = wid * 48;
  const int hbase = hg * 64;

  // line-coalesced B staging: base row = tid>>4, base col = (tid&15)*4 fp32
  const float* W1p = w1 + ((size_t)e * H_ + hbase + (tid >> 4)) * D_ + (tid & 15) * 4;
  const float* W3p = w3 + ((size_t)e * H_ + hbase + (tid >> 4)) * D_ + (tid & 15) * 4;

  for (int m0 = 0; m0 < count; m0 += BM_) {
    const int mc = count - m0;
    const unsigned short* arow[6];
#pragma unroll
    for (int i = 0; i < 6; ++i) {
      const int r = i * 32 + (tid >> 3);
      const int cr = (m0 + r < count) ? (m0 + r) : (count - 1);
      arow[i] = xb + (size_t)tok[off + cr] * D_ + (tid & 7) * 8;
    }
    const int q = mc - wm;
    const int mfn = (q <= 0) ? 0 : ((q + 15) >> 4 < 3 ? (q + 15) >> 4 : 3);

    f32x4 acc1[3][4] = {};
    f32x4 acc3[3][4] = {};

    u16x8 av[6];
    float4 b1v[4], b3v[4];

    for (int kt = 0; kt < D_; kt += 64) {
      __syncthreads();
      LOADR1(av, b1v, b3v, kt);
      WRITE1(av, b1v, b3v);
      __syncthreads();
      COMPUTE1();
    }

    // Epilogue: silu(h1)*h3 -> bf16 act
#pragma unroll
    for (int mf = 0; mf < 3; ++mf) {
#pragma unroll
      for (int r = 0; r < 4; ++r) {
        const int mrow = m0 + wm + mf * 16 + kg * 4 + r;
        if (mrow < count) {
          const size_t rb = (size_t)(off + mrow) * H_;
#pragma unroll
          for (int nf = 0; nf < 4; ++nf) {
            const float h1 = acc1[mf][nf][r];
            const float h3 = acc3[mf][nf][r];
            const float a = h1 / (1.f + __expf(-h1)) * h3;
            act[rb + hbase + nf * 16 + lr] = f2bf(a);
          }
        }
      }
    }
  }
}

#define LOADR2(AV, BV, KT) do {                                               \
    _Pragma("unroll")                                                         \
    for (int i = 0; i < 6; ++i) AV[i] = *reinterpret_cast<const u16x8*>(arow[i] + (KT)); \
    _Pragma("unroll")                                                         \
    for (int j = 0; j < 4; ++j)                                               \
      BV[j] = *reinterpret_cast<const float4*>(W2p + (KT) + j * 16 * H_);     \
  } while (0)

#define WRITE2(AV, BV) do {                                                   \
    _Pragma("unroll")                                                         \
    for (int i = 0; i < 6; ++i)                                               \
      *reinterpret_cast<u16x8*>(&As[i * 32 + (tid >> 3)][(tid & 7) * 8]) = AV[i]; \
    _Pragma("unroll")                                                         \
    for (int j = 0; j < 4; ++j)                                               \
      *reinterpret_cast<ushort4*>(&Bs[j * 16 + (tid >> 4)][(tid & 15) * 4]) = pack4(BV[j]); \
  } while (0)

#define COMPUTE2() do {                                                       \
    _Pragma("unroll")                                                         \
    for (int ks2 = 0; ks2 < 2; ++ks2) {                                       \
      const int kc = ks2 * 32 + kg * 8;                                       \
      bf16x8 af[3];                                                           \
      _Pragma("unroll")                                                       \
      for (int mf = 0; mf < 3; ++mf)                                          \
        af[mf] = *reinterpret_cast<const bf16x8*>(&As[wm + mf * 16 + lr][kc]); \
      _Pragma("unroll")                                                       \
      for (int nf = 0; nf < 4; ++nf) {                                        \
        bf16x8 bf = *reinterpret_cast<const bf16x8*>(&Bs[nf * 16 + lr][kc]);  \
        _Pragma("unroll")                                                     \
        for (int mf = 0; mf < 3; ++mf)                                        \
          if (mf < mfn)                                                       \
            acc[mf][nf] = __builtin_amdgcn_mfma_f32_16x16x32_bf16(af[mf], bf, acc[mf][nf], 0, 0, 0); \
      }                                                                       \
    }                                                                         \
  } while (0)

__launch_bounds__(256, 2)
__global__ void moe_ffn2(const unsigned short* __restrict__ act,
                         const float* __restrict__ w2,
                         const int* __restrict__ counts,
                         const int* __restrict__ offsets,
                         const float* __restrict__ coef,
                         float* __restrict__ part,
                         int kschunk) {
  const int bid = blockIdx.x;
  const int ks = bid >> 7;
  const int e = (bid >> 4) & 7;
  const int dg = bid & 15;
  const int count = counts[e];
  if (count <= 0) return;
  const int off = offsets[e];
  const int kbase = ks * kschunk;

  __shared__ unsigned short As[BM_][LDA_];
  __shared__ unsigned short Bs[64][LDA_];

  const int tid = threadIdx.x;
  const int lane = tid & 63, wid = tid >> 6;
  const int lr = lane & 15, kg = lane >> 4;
  const int wm = wid * 48;
  const int dbase = dg * 64;

  const float* W2p = w2 + ((size_t)e * D_ + dbase + (tid >> 4)) * H_ + kbase + (tid & 15) * 4;

  for (int m0 = 0; m0 < count; m0 += BM_) {
    const int mc = count - m0;
    const unsigned short* arow[6];
#pragma unroll
    for (int i = 0; i < 6; ++i) {
      const int r = i * 32 + (tid >> 3);
      const int cr = (m0 + r < count) ? (m0 + r) : (count - 1);
      arow[i] = act + (size_t)(off + cr) * H_ + kbase + (tid & 7) * 8;
    }
    const int q = mc - wm;
    const int mfn = (q <= 0) ? 0 : ((q + 15) >> 4 < 3 ? (q + 15) >> 4 : 3);

    f32x4 acc[3][4] = {};

    u16x8 av[6];
    float4 bv[4];

    for (int kt = 0; kt < kschunk; kt += 64) {
      __syncthreads();
      LOADR2(av, bv, kt);
      WRITE2(av, bv);
      __syncthreads();
      COMPUTE2();
    }

#pragma unroll
    for (int mf = 0; mf < 3; ++mf) {
#pragma unroll
      for (int r = 0; r < 4; ++r) {
        const int mrow = m0 + wm + mf * 16 + kg * 4 + r;
        if (mrow < count) {
          const float cf = coef[off + mrow];
          float* prow = part + ((size_t)ks * A_ + off + mrow) * D_;
#pragma unroll
          for (int nf = 0; nf < 4; ++nf)
            prow[dbase + nf * 16 + lr] = cf * acc[mf][nf][r];
        }
      }
    }
  }
}

// out[t] = sum over (ksn x 2 slots) partials in fixed order -> deterministic
__global__ void moe_combine(const float* __restrict__ part,
                            const int* __restrict__ slotof,
                            float* __restrict__ out,
                            int ksn) {
  const int t = blockIdx.x;
  const int i = threadIdx.x;  // 256 threads, float4 each
  const int g0 = slotof[2 * t], g1 = slotof[2 * t + 1];
  float4 o = make_float4(0.f, 0.f, 0.f, 0.f);
  for (int ks = 0; ks < ksn; ++ks) {
    const float* p = part + (size_t)ks * A_ * D_;
    float4 a = reinterpret_cast<const float4*>(p + (size_t)g0 * D_)[i];
    float4 b = reinterpret_cast<const float4*>(p + (size_t)g1 * D_)[i];
    o.x += a.x + b.x; o.y += a.y + b.y; o.z += a.z + b.z; o.w += a.w + b.w;
  }
  reinterpret_cast<float4*>(out + (size_t)t * D_)[i] = o;
}

extern "C" void kernel_launch(void* const* d_in, const int* in_sizes, int n_in,
                              void* d_out, int out_size, void* d_ws, size_t ws_size,
                              hipStream_t stream) {
  const float* x  = (const float*)d_in[0];
  const float* gw = (const float*)d_in[1];
  const float* w1 = (const float*)d_in[2];
  const float* w3 = (const float*)d_in[3];
  const float* w2 = (const float*)d_in[4];
  float* out = (float*)d_out;

  char* ws = (char*)d_ws;
  const size_t SM   = 32768;
  const size_t ACT  = (size_t)A_ * H_ * 2;   // 8 MB bf16
  const size_t XB   = (size_t)T_ * D_ * 2;   // 1 MB bf16
  const size_t P1   = (size_t)A_ * D_ * 4;   // 4 MB fp32 per K-split

  char* sm = ws;
  unsigned short* act = (unsigned short*)(ws + SM);
  unsigned short* xb  = (unsigned short*)(ws + SM + ACT);
  float* part         = (float*)(ws + SM + ACT + XB);
  const size_t base = SM + ACT + XB;
  const int ksn = (ws_size >= base + 4 * P1) ? 4 : (ws_size >= base + 2 * P1) ? 2 : 1;

  int*   sel     = (int*)  (sm);
  float* wtop    = (float*)(sm + 4096);
  int*   counts  = (int*)  (sm + 8192);
  int*   offsets = (int*)  (sm + 8192 + 64);
  int*   tokl    = (int*)  (sm + 12288);
  int*   slotof  = (int*)  (sm + 16384);
  float* coef    = (float*)(sm + 20480);

  moe_router <<<T_, 64, 0, stream>>>(x, gw, xb, sel, wtop);
  moe_compact<<<1, 512, 0, stream>>>(sel, wtop, counts, offsets, tokl, slotof, coef);
  moe_ffn1   <<<E_ * 64, 256, 0, stream>>>(xb, w1, w3, counts, offsets, tokl, act);
  moe_ffn2   <<<128 * ksn, 256, 0, stream>>>(act, w2, counts, offsets, coef, part, H_ / ksn);
  moe_combine<<<T_, 256, 0, stream>>>(part, slotof, out, ksn);
}

// Round 11
// 128.600 us; speedup vs baseline: 1.6641x; 1.3804x over previous
//
#include <hip/hip_runtime.h>
#include <hip/hip_bf16.h>

#define E_ 8
#define D_ 1024
#define H_ 4096
#define T_ 512
#define A_ 1024  // total assignments = T_ * top_k
#define BM_ 192  // covers count<=192 in one pass
#define LDA_ 72

typedef __attribute__((ext_vector_type(8))) short bf16x8;
typedef __attribute__((ext_vector_type(4))) float f32x4;
typedef __attribute__((ext_vector_type(8))) unsigned short u16x8;

__device__ __forceinline__ unsigned short f2bf(float f) {
  __hip_bfloat16 h = __float2bfloat16(f);
  return *reinterpret_cast<unsigned short*>(&h);
}

__device__ __forceinline__ bf16x8 pk8(float4 a, float4 b) {
  bf16x8 r;
  r[0] = (short)f2bf(a.x); r[1] = (short)f2bf(a.y);
  r[2] = (short)f2bf(a.z); r[3] = (short)f2bf(a.w);
  r[4] = (short)f2bf(b.x); r[5] = (short)f2bf(b.y);
  r[6] = (short)f2bf(b.z); r[7] = (short)f2bf(b.w);
  return r;
}

__device__ __forceinline__ u16x8 pack8(float4 a, float4 b) {
  u16x8 r;
  r[0] = f2bf(a.x); r[1] = f2bf(a.y); r[2] = f2bf(a.z); r[3] = f2bf(a.w);
  r[4] = f2bf(b.x); r[5] = f2bf(b.y); r[6] = f2bf(b.z); r[7] = f2bf(b.w);
  return r;
}

// async global->LDS, 16B per lane; dest = wave-uniform base + lane*16
__device__ __forceinline__ void gl16(const void* g, void* l) {
  __builtin_amdgcn_global_load_lds(
      (const __attribute__((address_space(1))) unsigned int*)g,
      (__attribute__((address_space(3))) unsigned int*)l, 16, 0, 0);
}

// ---------------- Router: logits -> softmax -> top2 -> renorm; x -> bf16 ----
__global__ void moe_router(const float* __restrict__ x,
                           const float* __restrict__ gw,
                           unsigned short* __restrict__ xb,
                           int* __restrict__ sel,
                           float* __restrict__ wtop) {
  const int t = blockIdx.x;
  const int lane = threadIdx.x;  // 64
  const float* xr = x + (size_t)t * D_;

  float4 xv[4];
#pragma unroll
  for (int i = 0; i < 4; ++i) xv[i] = *reinterpret_cast<const float4*>(xr + (i * 64 + lane) * 4);
#pragma unroll
  for (int i = 0; i < 4; ++i) {
    ushort4 u;
    u.x = f2bf(xv[i].x); u.y = f2bf(xv[i].y); u.z = f2bf(xv[i].z); u.w = f2bf(xv[i].w);
    *reinterpret_cast<ushort4*>(xb + (size_t)t * D_ + (i * 64 + lane) * 4) = u;
  }

  float lg[E_];
  for (int e = 0; e < E_; ++e) {
    const float* g = gw + (size_t)e * D_;
    float p = 0.f;
#pragma unroll
    for (int i = 0; i < 4; ++i) {
      float4 gv = *reinterpret_cast<const float4*>(g + (i * 64 + lane) * 4);
      p += xv[i].x * gv.x + xv[i].y * gv.y + xv[i].z * gv.z + xv[i].w * gv.w;
    }
#pragma unroll
    for (int off = 32; off; off >>= 1) p += __shfl_xor(p, off);
    lg[e] = p;
  }
  if (lane == 0) {
    float m = lg[0];
    for (int e = 1; e < E_; ++e) m = fmaxf(m, lg[e]);
    float pr[E_];
    float s = 0.f;
    for (int e = 0; e < E_; ++e) { pr[e] = __expf(lg[e] - m); s += pr[e]; }
    const float inv = 1.f / s;
    for (int e = 0; e < E_; ++e) pr[e] *= inv;
    float v0 = -1.f, v1 = -1.f; int i0 = 0, i1 = 0;
    for (int e = 0; e < E_; ++e) {
      float p = pr[e];
      if (p > v0)      { v1 = v0; i1 = i0; v0 = p; i0 = e; }
      else if (p > v1) { v1 = p; i1 = e; }
    }
    const float s2 = 1.f / (v0 + v1);
    sel[2 * t] = i0; sel[2 * t + 1] = i1;
    wtop[2 * t] = v0 * s2; wtop[2 * t + 1] = v1 * s2;
  }
}

// ---------------- Compaction: deterministic, order-preserving ---------------
__global__ void moe_compact(const int* __restrict__ sel,
                            const float* __restrict__ wtop,
                            int* __restrict__ counts,
                            int* __restrict__ offsets,
                            int* __restrict__ tok,
                            int* __restrict__ slotof,
                            float* __restrict__ coef) {
  const int tid = threadIdx.x;  // 512 = 8 waves; wave = expert
  const int e = tid >> 6;
  const int lane = tid & 63;
  __shared__ int cnt[E_], offs[E_];

  int base = 0;
  for (int c = 0; c < T_ / 64; ++c) {
    const int t = c * 64 + lane;
    const bool f = (sel[2 * t] == e) || (sel[2 * t + 1] == e);
    base += __popcll(__ballot(f));
  }
  if (lane == 0) cnt[e] = base;
  __syncthreads();
  if (tid == 0) {
    int o = 0;
    for (int i = 0; i < E_; ++i) { offs[i] = o; o += cnt[i]; }
  }
  __syncthreads();
  if (lane == 0) { counts[e] = cnt[e]; offsets[e] = offs[e]; }

  int pos = offs[e];
  for (int c = 0; c < T_ / 64; ++c) {
    const int t = c * 64 + lane;
    const int s0 = sel[2 * t], s1 = sel[2 * t + 1];
    const bool f = (s0 == e) || (s1 == e);
    unsigned long long b = __ballot(f);
    const int myp = pos + __popcll(b & ((1ull << lane) - 1ull));
    if (f) {
      const int k = (s0 == e) ? 0 : 1;
      tok[myp] = t;
      slotof[2 * t + k] = myp;
      coef[myp] = wtop[2 * t + k];
    }
    pos += __popcll(b);
  }
}

// ---------------- FFN1: round-4 gl_lds 2-phase double-buffered pipeline -----
// BK=32. A: bf16 [192][32] linear+XOR-swizzled. B: fp32 [64][32] swizzled,
// converted to bf16 at fragment read. 4 waves split M (48 rows each).
// LDS dest of gl_lds is linear; swizzle applied via per-lane SOURCE column
// (store side) and XOR'd read address (read side).

#define STAGE1(buf, kt) do {                                                  \
    _Pragma("unroll")                                                         \
    for (int j = 0; j < 3; ++j)                                               \
      gl16(asrc[j] + (kt), &As[buf][(j * 4 + wid) * 512]);                    \
    _Pragma("unroll")                                                         \
    for (int j = 0; j < 2; ++j) {                                             \
      gl16(b1src[j] + (kt), &B1s[buf][(j * 4 + wid) * 256]);                  \
      gl16(b3src[j] + (kt), &B3s[buf][(j * 4 + wid) * 256]);                  \
    }                                                                         \
  } while (0)

__launch_bounds__(256, 2)
__global__ void moe_ffn1(const unsigned short* __restrict__ xb,
                         const float* __restrict__ w1,
                         const float* __restrict__ w3,
                         const int* __restrict__ counts,
                         const int* __restrict__ offsets,
                         const int* __restrict__ tok,
                         unsigned short* __restrict__ act) {
  const int bid = blockIdx.x;
  const int hg = bid & 63;
  const int e = bid >> 6;
  const int count = counts[e];
  const int off = offsets[e];
  const int hbase = hg * 64;

  __shared__ unsigned short As[2][BM_ * 32];  // 2 x 12 KB
  __shared__ float B1s[2][64 * 32];           // 2 x 8 KB
  __shared__ float B3s[2][64 * 32];           // 2 x 8 KB

  const int tid = threadIdx.x;
  const int lane = tid & 63, wid = tid >> 6;
  const int lr = lane & 15, kg = lane >> 4;
  const int wm = wid * 48;

  // Staging source columns (pre-swizzled so linear LDS dest = swizzled layout)
  const int cA = (((lane & 3) ^ ((lane >> 3) & 3)) << 3);  // u16 elems
  const int cB = (((lane & 7) ^ ((lane >> 3) & 7)) << 2);  // f32 elems
  const float* b1src[2];
  const float* b3src[2];
#pragma unroll
  for (int j = 0; j < 2; ++j) {
    const int row = (j * 4 + wid) * 8 + (lane >> 3);
    b1src[j] = w1 + ((size_t)e * H_ + hbase + row) * D_ + cB;
    b3src[j] = w3 + ((size_t)e * H_ + hbase + row) * D_ + cB;
  }

  for (int m0 = 0; m0 < count; m0 += BM_) {
    const unsigned short* asrc[3];
#pragma unroll
    for (int j = 0; j < 3; ++j) {
      const int row = (j * 4 + wid) * 16 + (lane >> 2);
      const int cr = (m0 + row < count) ? (m0 + row) : (count - 1);
      asrc[j] = xb + (size_t)tok[off + cr] * D_ + cA;
    }
    const int q = count - m0 - wm;
    const int mfn = (q <= 0) ? 0 : ((q + 15) >> 4 < 3 ? (q + 15) >> 4 : 3);

    f32x4 acc1[3][4] = {};
    f32x4 acc3[3][4] = {};

    STAGE1(0, 0);
    __syncthreads();

    int cur = 0;
    const int pa = ((kg ^ ((lr >> 1) & 3)) << 3);
    const int q0 = (((kg * 2) ^ (lr & 7)) << 2);
    const int q1 = (((kg * 2 + 1) ^ (lr & 7)) << 2);
    for (int it = 0; it < 32; ++it) {
      if (it + 1 < 32) STAGE1(cur ^ 1, (it + 1) * 32);
      bf16x8 af[3];
#pragma unroll
      for (int mf = 0; mf < 3; ++mf)
        af[mf] = *reinterpret_cast<const bf16x8*>(&As[cur][(wm + mf * 16 + lr) * 32 + pa]);
#pragma unroll
      for (int nf = 0; nf < 4; ++nf) {
        const int rb = (nf * 16 + lr) * 32;
        bf16x8 b1f = pk8(*reinterpret_cast<const float4*>(&B1s[cur][rb + q0]),
                         *reinterpret_cast<const float4*>(&B1s[cur][rb + q1]));
        bf16x8 b3f = pk8(*reinterpret_cast<const float4*>(&B3s[cur][rb + q0]),
                         *reinterpret_cast<const float4*>(&B3s[cur][rb + q1]));
#pragma unroll
        for (int mf = 0; mf < 3; ++mf)
          if (mf < mfn) {
            acc1[mf][nf] = __builtin_amdgcn_mfma_f32_16x16x32_bf16(af[mf], b1f, acc1[mf][nf], 0, 0, 0);
            acc3[mf][nf] = __builtin_amdgcn_mfma_f32_16x16x32_bf16(af[mf], b3f, acc3[mf][nf], 0, 0, 0);
          }
      }
      if (it + 1 < 32) { __syncthreads(); cur ^= 1; }
    }

    // Epilogue: silu(h1)*h3 -> bf16 act
#pragma unroll
    for (int mf = 0; mf < 3; ++mf) {
#pragma unroll
      for (int r = 0; r < 4; ++r) {
        const int mrow = m0 + wm + mf * 16 + kg * 4 + r;
        if (mrow < count) {
          const size_t rb = (size_t)(off + mrow) * H_;
#pragma unroll
          for (int nf = 0; nf < 4; ++nf) {
            const float h1 = acc1[mf][nf][r];
            const float h3 = acc3[mf][nf][r];
            const float a = h1 / (1.f + __expf(-h1)) * h3;
            act[rb + hbase + nf * 16 + lr] = f2bf(a);
          }
        }
      }
    }
    __syncthreads();  // protect LDS before next m0 pass
  }
}

// ---------------- FFN2: round-3 barrier-staged grouped GEMM -----------------
__launch_bounds__(256, 2)
__global__ void moe_ffn2(const unsigned short* __restrict__ act,
                         const float* __restrict__ w2,
                         const int* __restrict__ counts,
                         const int* __restrict__ offsets,
                         const float* __restrict__ coef,
                         float* __restrict__ part,
                         int kschunk) {
  const int bid = blockIdx.x;
  const int ks = bid >> 7;
  const int e = (bid >> 4) & 7;
  const int dg = bid & 15;
  const int count = counts[e];
  if (count <= 0) return;
  const int off = offsets[e];
  const int kbase = ks * kschunk;

  __shared__ unsigned short As[BM_][LDA_];
  __shared__ unsigned short Bs[64][LDA_];

  const int tid = threadIdx.x;
  const int lane = tid & 63, wid = tid >> 6;
  const int lr = lane & 15, kg = lane >> 4;
  const int wm = wid * 48;
  const int dbase = dg * 64;

  const int brow = tid >> 2, bcol = (tid & 3) * 16;
  const float* W2p = w2 + ((size_t)e * D_ + dbase + brow) * H_ + kbase + bcol;

  for (int m0 = 0; m0 < count; m0 += BM_) {
    const int mc = count - m0;
    const unsigned short* arow[6];
#pragma unroll
    for (int i = 0; i < 6; ++i) {
      const int r = i * 32 + (tid >> 3);
      const int cr = (m0 + r < count) ? (m0 + r) : (count - 1);
      arow[i] = act + (size_t)(off + cr) * H_ + kbase + (tid & 7) * 8;
    }
    const int q = mc - wm;
    const int mfn = (q <= 0) ? 0 : ((q + 15) >> 4 < 3 ? (q + 15) >> 4 : 3);

    f32x4 acc[3][4] = {};

    for (int kt = 0; kt < kschunk; kt += 64) {
      __syncthreads();
      u16x8 av[6];
#pragma unroll
      for (int i = 0; i < 6; ++i) av[i] = *reinterpret_cast<const u16x8*>(arow[i] + kt);
      float4 bv[4];
#pragma unroll
      for (int i = 0; i < 4; ++i) bv[i] = *reinterpret_cast<const float4*>(W2p + kt + i * 4);
#pragma unroll
      for (int i = 0; i < 6; ++i)
        *reinterpret_cast<u16x8*>(&As[i * 32 + (tid >> 3)][(tid & 7) * 8]) = av[i];
#pragma unroll
      for (int i = 0; i < 2; ++i)
        *reinterpret_cast<u16x8*>(&Bs[brow][bcol + i * 8]) = pack8(bv[2 * i], bv[2 * i + 1]);
      __syncthreads();

#pragma unroll
      for (int ks2 = 0; ks2 < 2; ++ks2) {
        const int kc = ks2 * 32 + kg * 8;
        bf16x8 af[3];
#pragma unroll
        for (int mf = 0; mf < 3; ++mf)
          af[mf] = *reinterpret_cast<const bf16x8*>(&As[wm + mf * 16 + lr][kc]);
#pragma unroll
        for (int nf = 0; nf < 4; ++nf) {
          bf16x8 bf = *reinterpret_cast<const bf16x8*>(&Bs[nf * 16 + lr][kc]);
#pragma unroll
          for (int mf = 0; mf < 3; ++mf)
            if (mf < mfn)
              acc[mf][nf] = __builtin_amdgcn_mfma_f32_16x16x32_bf16(af[mf], bf, acc[mf][nf], 0, 0, 0);
        }
      }
    }

#pragma unroll
    for (int mf = 0; mf < 3; ++mf) {
#pragma unroll
      for (int r = 0; r < 4; ++r) {
        const int mrow = m0 + wm + mf * 16 + kg * 4 + r;
        if (mrow < count) {
          const float cf = coef[off + mrow];
          float* prow = part + ((size_t)ks * A_ + off + mrow) * D_;
#pragma unroll
          for (int nf = 0; nf < 4; ++nf)
            prow[dbase + nf * 16 + lr] = cf * acc[mf][nf][r];
        }
      }
    }
  }
}

// out[t] = sum over (ksn x 2 slots) partials in fixed order -> deterministic
__global__ void moe_combine(const float* __restrict__ part,
                            const int* __restrict__ slotof,
                            float* __restrict__ out,
                            int ksn) {
  const int t = blockIdx.x;
  const int i = threadIdx.x;  // 256 threads, float4 each
  const int g0 = slotof[2 * t], g1 = slotof[2 * t + 1];
  float4 o = make_float4(0.f, 0.f, 0.f, 0.f);
  for (int ks = 0; ks < ksn; ++ks) {
    const float* p = part + (size_t)ks * A_ * D_;
    float4 a = reinterpret_cast<const float4*>(p + (size_t)g0 * D_)[i];
    float4 b = reinterpret_cast<const float4*>(p + (size_t)g1 * D_)[i];
    o.x += a.x + b.x; o.y += a.y + b.y; o.z += a.z + b.z; o.w += a.w + b.w;
  }
  reinterpret_cast<float4*>(out + (size_t)t * D_)[i] = o;
}

extern "C" void kernel_launch(void* const* d_in, const int* in_sizes, int n_in,
                              void* d_out, int out_size, void* d_ws, size_t ws_size,
                              hipStream_t stream) {
  const float* x  = (const float*)d_in[0];
  const float* gw = (const float*)d_in[1];
  const float* w1 = (const float*)d_in[2];
  const float* w3 = (const float*)d_in[3];
  const float* w2 = (const float*)d_in[4];
  float* out = (float*)d_out;

  char* ws = (char*)d_ws;
  const size_t SM   = 32768;
  const size_t ACT  = (size_t)A_ * H_ * 2;   // 8 MB bf16
  const size_t XB   = (size_t)T_ * D_ * 2;   // 1 MB bf16
  const size_t P1   = (size_t)A_ * D_ * 4;   // 4 MB fp32 per K-split

  char* sm = ws;
  unsigned short* act = (unsigned short*)(ws + SM);
  unsigned short* xb  = (unsigned short*)(ws + SM + ACT);
  float* part         = (float*)(ws + SM + ACT + XB);
  const size_t base = SM + ACT + XB;
  const int ksn = (ws_size >= base + 4 * P1) ? 4 : (ws_size >= base + 2 * P1) ? 2 : 1;

  int*   sel     = (int*)  (sm);
  float* wtop    = (float*)(sm + 4096);
  int*   counts  = (int*)  (sm + 8192);
  int*   offsets = (int*)  (sm + 8192 + 64);
  int*   tokl    = (int*)  (sm + 12288);
  int*   slotof  = (int*)  (sm + 16384);
  float* coef    = (float*)(sm + 20480);

  moe_router <<<T_, 64, 0, stream>>>(x, gw, xb, sel, wtop);
  moe_compact<<<1, 512, 0, stream>>>(sel, wtop, counts, offsets, tokl, slotof, coef);
  moe_ffn1   <<<E_ * 64, 256, 0, stream>>>(xb, w1, w3, counts, offsets, tokl, act);
  moe_ffn2   <<<128 * ksn, 256, 0, stream>>>(act, w2, counts, offsets, coef, part, H_ / ksn);
  moe_combine<<<T_, 256, 0, stream>>>(part, slotof, out, ksn);
}